// Round 16
// baseline (160.705 us; speedup 1.0000x reference)
//
#include <hip/hip_runtime.h>
#include <hip/hip_cooperative_groups.h>

namespace cg = cooperative_groups;

// Problem constants (from reference)
#define B_ 32
#define C_ 32
#define T_ 8192
#define N_ 256
#define P_ 6
#define TV_ (T_ - P_ + 1)   // valid conv length = 8187

// =============================================================================
// ONE cooperative kernel: phase A decodes chars (BW-bound ~6us) + derives tabs
// in LDS; grid.sync(); phase B = r5-proven match+store loop (33us roofline).
// Removes ALL node gaps and the one-shot phase-exposure tax (r15: k_chars
// work is ~1-5us; the 28us was dispatch serialization).
// Fallback: if cooperative launch fails under graph capture, launch the r13
// two-kernel pipeline instead (61.5us known-good).
// =============================================================================

__global__ void k_coop(const float* __restrict__ inp,
                       const float* __restrict__ pat,
                       unsigned* __restrict__ chars32,
                       float* __restrict__ out) {
    __shared__ float4   s_part[256];      // 4 KB  phase-A partials
    __shared__ unsigned s_tabs[64 * 12];  // 3 KB  this block's 64-n tabs
    __shared__ unsigned s32[258];         // 1 KB  phase-B chars chunk

    int i   = blockIdx.x;                 // 0..1023
    int tid = threadIdx.x;
    int b   = i >> 5;                     // 0..31 (same b for phase A and B)
    int tA0 = (i & 31) << 8;              // phase-A 256-t chunk

    // ---- phase A: decode chars[b][tA0..tA0+255] (disjoint, 33 MB total) ----
    {
        int q  = tid & 63;                // t-quad
        int cgr = tid >> 6;               // 4 c-groups of 8
        const float* base = inp + (size_t)b * C_ * T_ + tA0 + (q << 2);
        float ax = 0.f, ay = 0.f, az = 0.f, aw = 0.f;
        #pragma unroll
        for (int k = 0; k < 8; ++k) {
            int c = (cgr << 3) + k;
            float4 v = *(const float4*)(base + (size_t)c * T_);
            float fc = (float)c;
            ax += fc * v.x; ay += fc * v.y; az += fc * v.z; aw += fc * v.w;
        }
        s_part[tid] = make_float4(ax, ay, az, aw);
    }
    __syncthreads();
    if (tid < 64) {
        float4 p0 = s_part[tid],       p1 = s_part[tid + 64],
               p2 = s_part[tid + 128], p3 = s_part[tid + 192];
        float sx = p0.x + p1.x + p2.x + p3.x;
        float sy = p0.y + p1.y + p2.y + p3.y;
        float sz = p0.z + p1.z + p2.z + p3.z;
        float sw = p0.w + p1.w + p2.w + p3.w;
        unsigned w = ((unsigned)(sx + 0.5f))
                   | ((unsigned)(sy + 0.5f) << 8)
                   | ((unsigned)(sz + 0.5f) << 16)
                   | ((unsigned)(sw + 0.5f) << 24);
        chars32[(((size_t)b * T_ + tA0) >> 2) + tid] = w;
    }

    // ---- phase-B identity + tab derivation (overlaps phase-A drain) ----
    int rem = i & 31;
    int tc  = rem & 7;                    // t-chunk 0..7
    int n0  = (rem >> 3) << 6;            // n-group base: 0,64,128,192
    if (tid < 192) {
        int p  = tid / 32;                // 0..5  (wave-uniform)
        int nl = tid & 31;
        #pragma unroll
        for (int h = 0; h < 2; ++h) {
            int n = n0 + nl + h * 32;
            float maxv = -3.402823466e+38f;
            float sum = 0.0f;
            unsigned mask = 0u;
            #pragma unroll
            for (int c = 0; c < C_; ++c) {
                float v = pat[((size_t)c * P_ + p) * N_ + n];
                sum += v;
                if (v > maxv) { maxv = v; mask = (1u << c); }
                else if (v == maxv) { mask |= (1u << c); }
            }
            if (!(sum > 0.0f)) mask = 0u;
            int pc = __popc(mask);
            unsigned req = (unsigned)(__ffs((int)mask) - 1);
            s_tabs[(nl + h * 32) * 12 + p]     = (pc == 1) ? req * 0x01010101u : 0x7F7F7F7Fu;
            s_tabs[(nl + h * 32) * 12 + 6 + p] = (pc == 0) ? 0u : 0x80808080u;
        }
    }

    cg::this_grid().sync();

    // ---- phase B: stage chars chunk -> LDS, byte-SIMD match, store ----
    int t0 = tc << 10;
    int tb = t0 + (tid << 2);
    const unsigned* csrc = chars32 + (((size_t)b * T_ + t0) >> 2);
    s32[tid] = csrc[tid];
    if (tid < 2) {
        unsigned v = 0u;
        int gt = t0 + 1024 + tid * 4;
        if (gt < T_) v = csrc[256 + tid];
        s32[256 + tid] = v;
    }
    __syncthreads();

    unsigned w0 = s32[tid], w1 = s32[tid + 1], w2 = s32[tid + 2];
    unsigned cw0 = w0;
    unsigned cw1 = __builtin_amdgcn_alignbyte(w1, w0, 1);
    unsigned cw2 = __builtin_amdgcn_alignbyte(w1, w0, 2);
    unsigned cw3 = __builtin_amdgcn_alignbyte(w1, w0, 3);
    unsigned cw4 = w1;
    unsigned cw5 = __builtin_amdgcn_alignbyte(w2, w1, 1);

    const uint4* tp = (const uint4*)s_tabs;
    float* obase = out + ((size_t)(b * N_ + n0)) * T_ + tb;
    bool tail = (tc == 7) && (tb + 3 >= TV_);

    #pragma unroll 4
    for (int g = 0; g < 64; ++g) {
        uint4 A  = tp[g * 3 + 0];         // xs0..xs3  (block-uniform broadcast)
        uint4 Bv = tp[g * 3 + 1];         // xs4, xs5, om0, om1
        uint4 Cv = tp[g * 3 + 2];         // om2..om5

        unsigned orv;
        orv  = ((cw0 ^ A.x)  + 0x7F7F7F7FU) & Bv.z;
        orv |= ((cw1 ^ A.y)  + 0x7F7F7F7FU) & Bv.w;   // v_and_or_b32
        orv |= ((cw2 ^ A.z)  + 0x7F7F7F7FU) & Cv.x;
        orv |= ((cw3 ^ A.w)  + 0x7F7F7F7FU) & Cv.y;
        orv |= ((cw4 ^ Bv.x) + 0x7F7F7F7FU) & Cv.z;
        orv |= ((cw5 ^ Bv.y) + 0x7F7F7F7FU) & Cv.w;

        float res[4];
        #pragma unroll
        for (int j = 0; j < 4; ++j)
            res[j] = (orv & (0x80u << (8 * j))) ? 0.0f : 1.0f;

        if (tail) {                       // only last chunk's tail lanes
            unsigned act = Bv.z | Bv.w | Cv.x | Cv.y | Cv.z | Cv.w;
            float padf = (act == 0u) ? 1.0f : 0.0f;  // psum==0: pad matches
            #pragma unroll
            for (int j = 0; j < 4; ++j)
                if (tb + j >= TV_) res[j] = padf;
        }

        float4 r; r.x = res[0]; r.y = res[1]; r.z = res[2]; r.w = res[3];
        *(float4*)(obase + (size_t)g * T_) = r;
    }
}

// ---------------------------------------------------------------------------
// Fallback pipeline (verbatim r13, 61.5us known-good)
// ---------------------------------------------------------------------------
__global__ void k_chars(const float* __restrict__ inp, unsigned* __restrict__ chars32) {
    int bx = blockIdx.x;
    int b  = bx >> 3;
    int t  = ((bx & 7) << 10) + (threadIdx.x << 2);
    const float* base = inp + (size_t)b * C_ * T_ + t;
    float ax = 0.f, ay = 0.f, az = 0.f, aw = 0.f;
    #pragma unroll
    for (int c = 0; c < C_; ++c) {
        float4 v = *(const float4*)(base + (size_t)c * T_);
        float fc = (float)c;
        ax += fc * v.x; ay += fc * v.y; az += fc * v.z; aw += fc * v.w;
    }
    unsigned w = ((unsigned)(ax + 0.5f))
               | ((unsigned)(ay + 0.5f) << 8)
               | ((unsigned)(az + 0.5f) << 16)
               | ((unsigned)(aw + 0.5f) << 24);
    chars32[((size_t)b * T_ + t) >> 2] = w;
}

__global__ void k_final(const unsigned char* __restrict__ chars,
                        const float* __restrict__ pat,
                        float* __restrict__ out) {
    __shared__ unsigned s32[258];
    __shared__ unsigned s_tabs[32 * 12];
    int tc  = blockIdx.x;
    int ng  = blockIdx.y;
    int b   = blockIdx.z;
    int tid = threadIdx.x;
    int t0  = tc << 10;
    int tb  = t0 + (tid << 2);
    int n0  = ng << 5;

    const unsigned* csrc = (const unsigned*)(chars + (size_t)b * T_ + t0);
    s32[tid] = csrc[tid];
    if (tid < 2) {
        unsigned v = 0u;
        int gt = t0 + 1024 + tid * 4;
        if (gt < T_) v = csrc[256 + tid];
        s32[256 + tid] = v;
    }
    if (tid < 192) {
        int nl = tid & 31;
        int p  = tid >> 5;
        int n  = n0 + nl;
        float maxv = -3.402823466e+38f;
        float sum = 0.0f;
        unsigned mask = 0u;
        #pragma unroll
        for (int c = 0; c < C_; ++c) {
            float v = pat[((size_t)c * P_ + p) * N_ + n];
            sum += v;
            if (v > maxv) { maxv = v; mask = (1u << c); }
            else if (v == maxv) { mask |= (1u << c); }
        }
        if (!(sum > 0.0f)) mask = 0u;
        int pc = __popc(mask);
        unsigned req = (unsigned)(__ffs((int)mask) - 1);
        s_tabs[nl * 12 + p]     = (pc == 1) ? req * 0x01010101u : 0x7F7F7F7Fu;
        s_tabs[nl * 12 + 6 + p] = (pc == 0) ? 0u : 0x80808080u;
    }
    __syncthreads();

    unsigned w0 = s32[tid], w1 = s32[tid + 1], w2 = s32[tid + 2];
    unsigned cw0 = w0;
    unsigned cw1 = __builtin_amdgcn_alignbyte(w1, w0, 1);
    unsigned cw2 = __builtin_amdgcn_alignbyte(w1, w0, 2);
    unsigned cw3 = __builtin_amdgcn_alignbyte(w1, w0, 3);
    unsigned cw4 = w1;
    unsigned cw5 = __builtin_amdgcn_alignbyte(w2, w1, 1);

    const uint4* tp = (const uint4*)s_tabs;
    float* obase = out + ((size_t)(b * N_ + n0)) * T_ + tb;
    bool tail = (tc == 7) && (tb + 3 >= TV_);

    #pragma unroll 4
    for (int g = 0; g < 32; ++g) {
        uint4 A  = tp[g * 3 + 0];
        uint4 Bv = tp[g * 3 + 1];
        uint4 Cv = tp[g * 3 + 2];

        unsigned orv;
        orv  = ((cw0 ^ A.x)  + 0x7F7F7F7FU) & Bv.z;
        orv |= ((cw1 ^ A.y)  + 0x7F7F7F7FU) & Bv.w;
        orv |= ((cw2 ^ A.z)  + 0x7F7F7F7FU) & Cv.x;
        orv |= ((cw3 ^ A.w)  + 0x7F7F7F7FU) & Cv.y;
        orv |= ((cw4 ^ Bv.x) + 0x7F7F7F7FU) & Cv.z;
        orv |= ((cw5 ^ Bv.y) + 0x7F7F7F7FU) & Cv.w;

        float res[4];
        #pragma unroll
        for (int j = 0; j < 4; ++j)
            res[j] = (orv & (0x80u << (8 * j))) ? 0.0f : 1.0f;

        if (tail) {
            unsigned act = Bv.z | Bv.w | Cv.x | Cv.y | Cv.z | Cv.w;
            float padf = (act == 0u) ? 1.0f : 0.0f;
            #pragma unroll
            for (int j = 0; j < 4; ++j)
                if (tb + j >= TV_) res[j] = padf;
        }

        float4 r; r.x = res[0]; r.y = res[1]; r.z = res[2]; r.w = res[3];
        *(float4*)(obase + (size_t)g * T_) = r;
    }
}

// ---------------------------------------------------------------------------
extern "C" void kernel_launch(void* const* d_in, const int* in_sizes, int n_in,
                              void* d_out, int out_size, void* d_ws, size_t ws_size,
                              hipStream_t stream) {
    const float* input_   = (const float*)d_in[0];   // (B,C,T,1) one-hot fp32
    const float* patterns = (const float*)d_in[1];   // (C,P,1,N) fp32
    float* out = (float*)d_out;                      // (B,N,T,1) fp32

    unsigned* chars32 = (unsigned*)((char*)d_ws + 16384);

    void* args[] = { (void*)&input_, (void*)&patterns, (void*)&chars32, (void*)&out };
    hipError_t err = hipLaunchCooperativeKernel((const void*)k_coop,
                                                dim3(1024), dim3(256),
                                                args, 0, stream);
    if (err != hipSuccess) {
        // Fallback: r13 two-node pipeline (61.5us known-good)
        hipLaunchKernelGGL(k_chars, dim3(B_ * (T_ / 1024)), dim3(256), 0, stream,
                           input_, chars32);
        hipLaunchKernelGGL(k_final, dim3(T_ / 1024, N_ / 32, B_), dim3(256), 0, stream,
                           (const unsigned char*)chars32, patterns, out);
    }
}

// Round 17
// 73.468 us; speedup vs baseline: 2.1874x; 2.1874x over previous
//
#include <hip/hip_runtime.h>

// Problem constants (from reference)
#define B_ 32
#define C_ 32
#define T_ 8192
#define N_ 256
#define P_ 6
#define TV_ (T_ - P_ + 1)   // valid conv length = 8187
#define TILE_T 128
#define NBLK 1024           // 4 blocks/CU, all co-resident
#define ITERS 2             // tiles per block: i and i+NBLK

// ---------------------------------------------------------------------------
// Kernel 0 (verbatim r5): discretize patterns -> byte-SIMD match tables.
// tabs[n][12]: dwords 0..5 = xs[p] (XOR splat), 6..11 = om[p] (active mask).
// ---------------------------------------------------------------------------
__global__ void k_disc(const float* __restrict__ pat, unsigned* __restrict__ tabs) {
    int tid = blockIdx.x * blockDim.x + threadIdx.x;
    if (tid >= P_ * N_) return;
    int p = tid / N_;
    int n = tid - p * N_;
    float maxv = -3.402823466e+38f;
    float sum = 0.0f;
    unsigned mask = 0u;
    #pragma unroll
    for (int c = 0; c < C_; ++c) {
        float v = pat[((size_t)c * P_ + p) * N_ + n];
        sum += v;
        if (v > maxv) { maxv = v; mask = (1u << c); }
        else if (v == maxv) { mask |= (1u << c); }
    }
    if (!(sum > 0.0f)) mask = 0u;
    int pc = __popc(mask);
    unsigned req = (unsigned)(__ffs((int)mask) - 1);
    unsigned xs = (pc == 1) ? req * 0x01010101u : 0x7F7F7F7Fu;
    unsigned om = (pc == 0) ? 0u : 0x80808080u;
    tabs[n * 12 + p]     = xs;
    tabs[n * 12 + 6 + p] = om;
}

// ---------------------------------------------------------------------------
// k_pipe: r10's proven decode/reduce/match bodies, but each block processes
// TWO tiles in sequence (i, i+1024). Tile-1's decode loads issue while
// tile-0's stores drain (stores are fire-and-forget) -> the r11 steady-state
// overlap (16us marginal) manufactured INSIDE one dispatch, instead of
// hoping CP backfill staggers phases (r10/r14: it doesn't).
// ---------------------------------------------------------------------------
__global__ void k_pipe(const float* __restrict__ inp,
                       const unsigned* __restrict__ tabs,
                       float* __restrict__ out) {
    __shared__ uint4    s_tabs4[768];     // 12 KB
    __shared__ float4   s_part[8][32];    // 4 KB  (cg x quad partial sums)
    __shared__ float4   s_hpart[8][2];    // halo partials
    __shared__ unsigned s32[2][34];       // double-buffered chars (+halo)

    int tid  = threadIdx.x;
    int quad = tid & 31;                  // t-quad within tile
    int cg   = tid >> 5;                  // c-group / n-group 0..7

    // ---- stage tabs -> LDS once (3 coalesced uint4 per thread) ----
    {
        const uint4* g = (const uint4*)tabs;
        s_tabs4[tid]       = g[tid];
        s_tabs4[tid + 256] = g[tid + 256];
        s_tabs4[tid + 512] = g[tid + 512];
    }

    for (int it = 0; it < ITERS; ++it) {
        int tile = blockIdx.x + it * NBLK;   // 0..2047
        int b    = tile >> 6;                // 64 tiles per b-row
        int tc   = tile & 63;
        int t0   = tc << 7;

        // ---- decode: thread (quad, cg) sums 4 c-rows at its 4 t's ----
        {
            int t = t0 + (quad << 2);
            const float* base = inp + (size_t)b * C_ * T_ + t;
            float ax = 0.f, ay = 0.f, az = 0.f, aw = 0.f;
            #pragma unroll
            for (int i = 0; i < 4; ++i) {
                int c = (cg << 2) + i;
                float4 v = *(const float4*)(base + (size_t)c * T_);
                float fc = (float)c;
                ax += fc * v.x; ay += fc * v.y; az += fc * v.z; aw += fc * v.w;
            }
            s_part[cg][quad] = make_float4(ax, ay, az, aw);
            if (quad < 2) {                   // halo t0+128 .. t0+135
                int th = t0 + TILE_T + (quad << 2);
                float hx = 0.f, hy = 0.f, hz = 0.f, hw = 0.f;
                if (th + 3 < T_) {            // tc==63: OOB -> zeros (pad region)
                    const float* hb = inp + (size_t)b * C_ * T_ + th;
                    #pragma unroll
                    for (int i = 0; i < 4; ++i) {
                        int c = (cg << 2) + i;
                        float4 v = *(const float4*)(hb + (size_t)c * T_);
                        float fc = (float)c;
                        hx += fc * v.x; hy += fc * v.y; hz += fc * v.z; hw += fc * v.w;
                    }
                }
                s_hpart[cg][quad] = make_float4(hx, hy, hz, hw);
            }
        }
        __syncthreads();

        // ---- reduce 8 c-group partials -> packed chars words ----
        if (tid < 32) {
            float sx = 0.f, sy = 0.f, sz = 0.f, sw = 0.f;
            #pragma unroll
            for (int k = 0; k < 8; ++k) {
                float4 p = s_part[k][tid];
                sx += p.x; sy += p.y; sz += p.z; sw += p.w;
            }
            s32[it & 1][tid] = ((unsigned)(sx + 0.5f))
                             | ((unsigned)(sy + 0.5f) << 8)
                             | ((unsigned)(sz + 0.5f) << 16)
                             | ((unsigned)(sw + 0.5f) << 24);
        } else if (tid < 34) {
            int hq = tid - 32;
            float sx = 0.f, sy = 0.f, sz = 0.f, sw = 0.f;
            #pragma unroll
            for (int k = 0; k < 8; ++k) {
                float4 p = s_hpart[k][hq];
                sx += p.x; sy += p.y; sz += p.z; sw += p.w;
            }
            s32[it & 1][32 + hq] = ((unsigned)(sx + 0.5f))
                                 | ((unsigned)(sy + 0.5f) << 8)
                                 | ((unsigned)(sz + 0.5f) << 16)
                                 | ((unsigned)(sw + 0.5f) << 24);
        }
        __syncthreads();

        // ---- match: thread = (quad, ng=cg); 32 n per thread ----
        const unsigned* sc = s32[it & 1];
        unsigned w0 = sc[quad], w1 = sc[quad + 1], w2 = sc[quad + 2];
        unsigned cw0 = w0;
        unsigned cw1 = __builtin_amdgcn_alignbyte(w1, w0, 1);
        unsigned cw2 = __builtin_amdgcn_alignbyte(w1, w0, 2);
        unsigned cw3 = __builtin_amdgcn_alignbyte(w1, w0, 3);
        unsigned cw4 = w1;
        unsigned cw5 = __builtin_amdgcn_alignbyte(w2, w1, 1);

        int tb = t0 + (quad << 2);
        int n0 = cg << 5;
        float* obase = out + ((size_t)(b * N_ + n0)) * T_ + tb;
        bool tail = (tc == 63) && (tb + 3 >= TV_);

        #pragma unroll 4
        for (int g = 0; g < 32; ++g) {
            uint4 A  = s_tabs4[(n0 + g) * 3 + 0];   // xs0..xs3
            uint4 Bv = s_tabs4[(n0 + g) * 3 + 1];   // xs4, xs5, om0, om1
            uint4 Cv = s_tabs4[(n0 + g) * 3 + 2];   // om2..om5

            unsigned orv;
            orv  = ((cw0 ^ A.x)  + 0x7F7F7F7FU) & Bv.z;
            orv |= ((cw1 ^ A.y)  + 0x7F7F7F7FU) & Bv.w;   // v_and_or_b32
            orv |= ((cw2 ^ A.z)  + 0x7F7F7F7FU) & Cv.x;
            orv |= ((cw3 ^ A.w)  + 0x7F7F7F7FU) & Cv.y;
            orv |= ((cw4 ^ Bv.x) + 0x7F7F7F7FU) & Cv.z;
            orv |= ((cw5 ^ Bv.y) + 0x7F7F7F7FU) & Cv.w;

            float res[4];
            #pragma unroll
            for (int j = 0; j < 4; ++j)
                res[j] = (orv & (0x80u << (8 * j))) ? 0.0f : 1.0f;

            if (tail) {                       // only tc==63's last quads
                unsigned act = Bv.z | Bv.w | Cv.x | Cv.y | Cv.z | Cv.w;
                float padf = (act == 0u) ? 1.0f : 0.0f;  // psum==0: pad matches
                #pragma unroll
                for (int j = 0; j < 4; ++j)
                    if (tb + j >= TV_) res[j] = padf;
            }

            float4 r; r.x = res[0]; r.y = res[1]; r.z = res[2]; r.w = res[3];
            *(float4*)(obase + (size_t)g * T_) = r;
        }
        // next iteration's decode loads issue here while these stores drain
    }
}

// ---------------------------------------------------------------------------
extern "C" void kernel_launch(void* const* d_in, const int* in_sizes, int n_in,
                              void* d_out, int out_size, void* d_ws, size_t ws_size,
                              hipStream_t stream) {
    const float* input_   = (const float*)d_in[0];   // (B,C,T,1) one-hot fp32
    const float* patterns = (const float*)d_in[1];   // (C,P,1,N) fp32
    float* out = (float*)d_out;                      // (B,N,T,1) fp32

    unsigned* tabs = (unsigned*)d_ws;                // [0, 12288)

    hipLaunchKernelGGL(k_disc, dim3((P_ * N_ + 255) / 256), dim3(256), 0, stream,
                       patterns, tabs);
    hipLaunchKernelGGL(k_pipe, dim3(NBLK), dim3(256), 0, stream,
                       input_, tabs, out);
}